// Round 1
// 274.375 us; speedup vs baseline: 1.0220x; 1.0220x over previous
//
#include <hip/hip_runtime.h>
#include <cstdint>
#include <cstddef>

typedef unsigned int u32;
typedef unsigned short u16;
typedef __attribute__((ext_vector_type(8))) short short8;   // 8 bf16 = 4 VGPRs (MFMA A/B frag)
typedef __attribute__((ext_vector_type(4))) float f32x4;    // MFMA C/D frag

#define S_LEN 1024
#define BATCH 16
#define NHEAD 8
#define DMODEL 512
#define KHD 64
#define NROW (S_LEN * BATCH)          // 16384 GEMM rows

__device__ __forceinline__ u16 f2bf(float f) {
    u32 u = __float_as_uint(f);
    return (u16)((u + 0x7fffu + ((u >> 16) & 1u)) >> 16);   // RTNE
}

__device__ __forceinline__ void gl_lds16(const void* g, void* l) {
    __builtin_amdgcn_global_load_lds(
        (const __attribute__((address_space(1))) void*)(uintptr_t)g,
        (__attribute__((address_space(3))) void*)(uintptr_t)l, 16, 0, 0);
}

// ---------------------------------------------------------------------------
// Weights fp32 -> bf16, packed [4][512*512] into ws.
// ---------------------------------------------------------------------------
__global__ __launch_bounds__(256) void wcvt_kernel(
    const float* __restrict__ WQ, const float* __restrict__ WK,
    const float* __restrict__ WV, const float* __restrict__ Wo,
    u16* __restrict__ dst)
{
    const int m = blockIdx.y;
    const float* __restrict__ src = (m == 0) ? WQ : (m == 1) ? WK : (m == 2) ? WV : Wo;
    const int idx = (blockIdx.x * 256 + threadIdx.x) * 4;
    const float4 v = *(const float4*)(src + idx);
    u16 r[4];
    r[0] = f2bf(v.x); r[1] = f2bf(v.y); r[2] = f2bf(v.z); r[3] = f2bf(v.w);
    *(uint2*)(dst + (size_t)m * DMODEL * DMODEL + idx) = *(uint2*)r;
}

// ---------------------------------------------------------------------------
// Activation fp32 -> bf16 (layout-preserving). blockIdx.y picks s0/s1 and the
// destination half (dst + y*NROW*DMODEL).
// ---------------------------------------------------------------------------
__global__ __launch_bounds__(256) void xcvt_kernel(
    const float* __restrict__ s0, const float* __restrict__ s1,
    u16* __restrict__ dst)
{
    const float* __restrict__ src = (blockIdx.y == 0) ? s0 : s1;
    u16* d = dst + (size_t)blockIdx.y * NROW * DMODEL;
    const int idx = (blockIdx.x * 256 + threadIdx.x) * 4;
    const float4 v = *(const float4*)(src + idx);
    u16 r[4];
    r[0] = f2bf(v.x); r[1] = f2bf(v.y); r[2] = f2bf(v.z); r[3] = f2bf(v.w);
    *(uint2*)(d + idx) = *(uint2*)r;
}

// ---------------------------------------------------------------------------
// bf16-MFMA GEMM, 128x128 tile, BK=64. A and B both staged via
// global_load_lds width=16 with XOR chunk swizzle in the GLOBAL address
// (LDS side lane-contiguous) -> conflict-free b128 frag reads, zero VALU
// conversion in the K-loop.
// M==0: fp32 out to outP.                                 grid (128,4,1)
// M==1: per-head L2 norm, bf16 out [B][H][S][64], z=q/k.  grid (128,4,2)
// M==2: per-head L2 norm, V transposed out [B][H][64][S]. grid (8,4,16)
//       A rows are consecutive s for batch bb (astr = B*D).
// ---------------------------------------------------------------------------
template<int M>
__global__ __launch_bounds__(256) void gemm_kernel(
    const u16* __restrict__ Abf,    // bf16 A base (M1: +z*NROW*D; M2: +bb*D)
    const u16* __restrict__ Wb,     // bf16 weight panel (M1: +z*D*D inside)
    u16* __restrict__ outN,
    float* __restrict__ outP)
{
    __shared__ __align__(16) u16 Alds[128 * 64];
    __shared__ __align__(16) u16 Blds[128 * 64];

    const int tid  = threadIdx.x;
    const int wave = tid >> 6;
    const int lane = tid & 63;
    const int m16  = lane & 15;
    const int quad = lane >> 4;
    const int wm   = wave >> 1;
    const int wn   = wave & 1;
    const int n0   = blockIdx.y * 128;
    const int row0 = blockIdx.x * 128;
    const int z    = (M == 1) ? blockIdx.z : 0;
    const int bb   = (M == 2) ? blockIdx.z : 0;

    const u16* __restrict__ A = Abf + (size_t)z * NROW * DMODEL + (size_t)bb * DMODEL;
    const size_t astr = (M == 2) ? (size_t)BATCH * DMODEL : (size_t)DMODEL;
    const u16* __restrict__ B = Wb + ((M == 1) ? (size_t)z * DMODEL * DMODEL : 0);

    f32x4 acc[4][4] = {};

    const int brow   = lane >> 3;              // 0..7
    const int bchunk = (lane & 7) ^ brow;      // XOR chunk swizzle

    for (int kt = 0; kt < DMODEL; kt += 64) {
        __syncthreads();   // previous-iteration frag reads done
        {
            const u16* ap = A + (size_t)(row0 + wave * 32 + brow) * astr + kt + bchunk * 8;
            const u16* bp = B + (size_t)(n0 + wave * 32 + brow) * DMODEL + kt + bchunk * 8;
            u16* la = &Alds[(wave * 32) * 64];
            u16* lb = &Blds[(wave * 32) * 64];
#pragma unroll
            for (int j = 0; j < 4; j++) {
                gl_lds16(ap + (size_t)j * 8 * astr,   la + j * 8 * 64);
                gl_lds16(bp + (size_t)j * 8 * DMODEL, lb + j * 8 * 64);
            }
        }
        __syncthreads();   // drains vmcnt: tiles visible

#pragma unroll
        for (int half = 0; half < 2; half++) {
            short8 af[4], bfr[4];
#pragma unroll
            for (int mt = 0; mt < 4; mt++)
                af[mt] = *(const short8*)&Alds[(wm * 64 + mt * 16 + m16) * 64 +
                                               (((half << 2) + quad) ^ (m16 & 7)) * 8];
#pragma unroll
            for (int nt = 0; nt < 4; nt++)
                bfr[nt] = *(const short8*)&Blds[(wn * 64 + nt * 16 + m16) * 64 +
                                                (((half << 2) + quad) ^ (m16 & 7)) * 8];
#pragma unroll
            for (int mt = 0; mt < 4; mt++)
#pragma unroll
                for (int nt = 0; nt < 4; nt++)
                    acc[mt][nt] = __builtin_amdgcn_mfma_f32_16x16x32_bf16(af[mt], bfr[nt], acc[mt][nt], 0, 0, 0);
        }
    }

    if (M == 1) {
        const int h = (n0 >> 6) + wn;
        u16* outZ = outN + (size_t)z * BATCH * NHEAD * S_LEN * KHD;
#pragma unroll
        for (int mt = 0; mt < 4; mt++) {
#pragma unroll
            for (int r = 0; r < 4; r++) {
                float ss = 0.0f;
#pragma unroll
                for (int nt = 0; nt < 4; nt++) ss += acc[mt][nt][r] * acc[mt][nt][r];
                ss += __shfl_xor(ss, 1);
                ss += __shfl_xor(ss, 2);
                ss += __shfl_xor(ss, 4);
                ss += __shfl_xor(ss, 8);
                const float sc = 1.0f / fmaxf(sqrtf(ss), 1e-12f);
                const int i = row0 + wm * 64 + mt * 16 + quad * 4 + r;
                const int s = i >> 4, b = i & 15;
                u16* op = outZ + (((size_t)b * NHEAD + h) * S_LEN + s) * KHD;
#pragma unroll
                for (int nt = 0; nt < 4; nt++)
                    op[nt * 16 + m16] = f2bf(acc[mt][nt][r] * sc);
            }
        }
    } else if (M == 2) {
        const int h = (n0 >> 6) + wn;
#pragma unroll
        for (int mt = 0; mt < 4; mt++) {
            float scl[4];
#pragma unroll
            for (int r = 0; r < 4; r++) {
                float ss = 0.0f;
#pragma unroll
                for (int nt = 0; nt < 4; nt++) ss += acc[mt][nt][r] * acc[mt][nt][r];
                ss += __shfl_xor(ss, 1);
                ss += __shfl_xor(ss, 2);
                ss += __shfl_xor(ss, 4);
                ss += __shfl_xor(ss, 8);
                scl[r] = 1.0f / fmaxf(sqrtf(ss), 1e-12f);
            }
            const int sbase = row0 + wm * 64 + mt * 16 + quad * 4;
#pragma unroll
            for (int nt = 0; nt < 4; nt++) {
                const int vcol = nt * 16 + m16;
                uint2 pk;
                pk.x = (u32)f2bf(acc[mt][nt][0] * scl[0]) |
                       ((u32)f2bf(acc[mt][nt][1] * scl[1]) << 16);
                pk.y = (u32)f2bf(acc[mt][nt][2] * scl[2]) |
                       ((u32)f2bf(acc[mt][nt][3] * scl[3]) << 16);
                u16* dp = outN + (((size_t)bb * NHEAD + h) * KHD + vcol) * S_LEN + sbase;
                *(uint2*)dp = pk;
            }
        }
    } else {
#pragma unroll
        for (int mt = 0; mt < 4; mt++) {
#pragma unroll
            for (int r = 0; r < 4; r++) {
                const int i = row0 + wm * 64 + mt * 16 + quad * 4 + r;
                float* op = outP + (size_t)i * DMODEL + n0 + wn * 64;
#pragma unroll
                for (int nt = 0; nt < 4; nt++)
                    op[nt * 16 + m16] = acc[mt][nt][r];
            }
        }
    }
}

// ---------------------------------------------------------------------------
// Attention v4. 64 q/block (16 per wave), 64-key iters, grid (128,16):
//   blockIdx.x = bh so all 16 q-tiles of one head land on ONE XCD
//   (linear%8 = bh%8); per-XCD K/V working set = 16 heads x 256KB = 4MB = L2.
// Double-buffered K/V: stage(next) -> compute(cur) -> barrier. One barrier
// per iter, load latency hidden under ~450 cy of MFMA/VALU (T3-minimum).
// Plds: stride 64 with 16B-chunk XOR swizzle (byte chunk ^= m16&7) ->
// conflict-free AND total LDS exactly 40KB -> 4 blocks/CU (16 waves).
// Scores = cos/8 in [-0.125,0.125]:
//   p = exp(y/8) via cubic Taylor (3 FMA, err ~1e-5 << bf16 ulp)
//   P packed by TRUNCATION (cheap); row-sum via an extra ones-MFMA
//   on the bf16 P itself -> exact num/denom consistency, zero shuffles.
// Output: bf16 concat [S][B][H*K] -> Xc (= d_out scratch).
// ---------------------------------------------------------------------------
__global__ __launch_bounds__(256) void attn_kernel(
    const u16* __restrict__ wq, const u16* __restrict__ wk, const u16* __restrict__ wvT,
    u16* __restrict__ Xc)
{
    __shared__ __align__(16) u16 Klds[2][64 * 64];    // [buf][key][dim], XOR chunks
    __shared__ __align__(16) u16 Vlds[2][64 * 64];    // [buf][vcol][key], XOR chunks
    __shared__ __align__(16) u16 Plds[4][16 * 64];    // per-wave [q16][key64], XOR chunks

    const int tid  = threadIdx.x;
    const int wave = tid >> 6;
    const int lane = tid & 63;
    const int m16  = lane & 15;
    const int quad = lane >> 4;
    const int bh   = blockIdx.x;        // 0..127  (XCD = bh % 8)
    const int qt   = blockIdx.y;        // 16 tiles of 64 q

    const u16* Qb = wq  + (size_t)bh * S_LEN * KHD;
    const u16* Kb = wk  + (size_t)bh * S_LEN * KHD;
    const u16* Vb = wvT + (size_t)bh * KHD * S_LEN;

    const int qrow = qt * 64 + wave * 16 + m16;
    const short8 qf0 = *(const short8*)(Qb + (size_t)qrow * KHD + quad * 8);
    const short8 qf1 = *(const short8*)(Qb + (size_t)qrow * KHD + 32 + quad * 8);

    short8 ones;
#pragma unroll
    for (int j = 0; j < 8; j++) ones[j] = (short)0x3F80;   // bf16 1.0

    f32x4 o[4] = {};    // D[m=vcol][n=q]
    f32x4 ls  = {};     // ones-MFMA row-sum accumulator (all regs identical)
    const float C1 = 0.125f, C2 = 0.0078125f, C3 = 3.2552083e-4f;

    const int srow   = lane >> 3;
    const int schunk = (lane & 7) ^ srow;
    const int r0     = wave * 8 + srow;

    // prologue: stage tile 0 into buf 0
    gl_lds16(Kb + (size_t)r0 * KHD + schunk * 8,               &Klds[0][(wave * 8) * 64]);
    gl_lds16(Kb + (size_t)(r0 + 32) * KHD + schunk * 8,        &Klds[0][(wave * 8 + 32) * 64]);
    gl_lds16(Vb + (size_t)r0 * S_LEN + schunk * 8,             &Vlds[0][(wave * 8) * 64]);
    gl_lds16(Vb + (size_t)(r0 + 32) * S_LEN + schunk * 8,      &Vlds[0][(wave * 8 + 32) * 64]);
    __syncthreads();

    for (int it = 0; it < S_LEN / 64; it++) {
        const int cur = it & 1;

        // stage NEXT tile into the other buffer; latency hides under compute
        if (it + 1 < S_LEN / 64) {
            const int nxt = cur ^ 1;
            const int kt0 = (it + 1) * 64;
            gl_lds16(Kb + (size_t)(kt0 + r0) * KHD + schunk * 8,        &Klds[nxt][(wave * 8) * 64]);
            gl_lds16(Kb + (size_t)(kt0 + r0 + 32) * KHD + schunk * 8,   &Klds[nxt][(wave * 8 + 32) * 64]);
            gl_lds16(Vb + (size_t)r0 * S_LEN + kt0 + schunk * 8,        &Vlds[nxt][(wave * 8) * 64]);
            gl_lds16(Vb + (size_t)(r0 + 32) * S_LEN + kt0 + schunk * 8, &Vlds[nxt][(wave * 8 + 32) * 64]);
        }

        // S^T: D[m=key][n=q] = K x Q^T; p = exp(y/8) poly; truncate-pack
#pragma unroll
        for (int mt = 0; mt < 4; mt++) {
            const short8 kf0 = *(const short8*)&Klds[cur][(mt * 16 + m16) * 64 + (quad ^ (m16 & 7)) * 8];
            const short8 kf1 = *(const short8*)&Klds[cur][(mt * 16 + m16) * 64 + ((4 + quad) ^ (m16 & 7)) * 8];
            f32x4 c = {};
            c = __builtin_amdgcn_mfma_f32_16x16x32_bf16(kf0, qf0, c, 0, 0, 0);
            c = __builtin_amdgcn_mfma_f32_16x16x32_bf16(kf1, qf1, c, 0, 0, 0);
            u32 up[4];
#pragma unroll
            for (int r = 0; r < 4; r++) {
                const float y = c[r];
                const float p = fmaf(fmaf(fmaf(C3, y, C2), y, C1), y, 1.0f);
                up[r] = __float_as_uint(p);
            }
            uint2 pk;
            pk.x = (up[0] >> 16) | (up[1] & 0xffff0000u);
            pk.y = (up[2] >> 16) | (up[3] & 0xffff0000u);
            // logical byte off = m16*128 + (2mt + quad>>1)*16 + (quad&1)*8,
            // physical 16B chunk XOR'd by m16&7 (matched on read)
            u16* pwp = (u16*)((char*)Plds[wave] + m16 * 128 +
                              ((((mt << 1) + (quad >> 1)) ^ (m16 & 7)) << 4) + ((quad & 1) << 3));
            *(uint2*)pwp = pk;
        }

        // PV + ones-MFMA row-sum (wave-private P, no barrier)
        __builtin_amdgcn_s_setprio(1);
#pragma unroll
        for (int c = 0; c < 2; c++) {
            const short8 pb = *(const short8*)((const char*)Plds[wave] + m16 * 128 +
                                               (((c * 4 + quad) ^ (m16 & 7)) << 4));
            ls = __builtin_amdgcn_mfma_f32_16x16x32_bf16(ones, pb, ls, 0, 0, 0);
#pragma unroll
            for (int vt = 0; vt < 4; vt++) {
                const short8 vf = *(const short8*)&Vlds[cur][(vt * 16 + m16) * 64 +
                                                             (((c << 2) + quad) ^ (m16 & 7)) * 8];
                o[vt] = __builtin_amdgcn_mfma_f32_16x16x32_bf16(vf, pb, o[vt], 0, 0, 0);
            }
        }
        __builtin_amdgcn_s_setprio(0);

        __syncthreads();   // drains vmcnt (next tile visible) + frees cur buf
    }

    // epilogue: lane's q = m16 (all ls regs hold that q's row-sum)
    const float inv = 1.0f / ls[0];
    const int b = bh >> 3, h = bh & 7;
    u16* cp = Xc + ((size_t)qrow * BATCH + b) * (NHEAD * KHD) + h * KHD;
#pragma unroll
    for (int vt = 0; vt < 4; vt++) {
        uint2 pk;
        pk.x = (u32)f2bf(o[vt][0] * inv) | ((u32)f2bf(o[vt][1] * inv) << 16);
        pk.y = (u32)f2bf(o[vt][2] * inv) | ((u32)f2bf(o[vt][3] * inv) << 16);
        *(uint2*)(cp + vt * 16 + quad * 4) = pk;
    }
}

extern "C" void kernel_launch(void* const* d_in, const int* in_sizes, int n_in,
                              void* d_out, int out_size, void* d_ws, size_t ws_size,
                              hipStream_t stream) {
    const float* q    = (const float*)d_in[0];
    const float* k    = (const float*)d_in[1];
    const float* v    = (const float*)d_in[2];
    const float* WQ   = (const float*)d_in[3];
    const float* WK   = (const float*)d_in[4];
    const float* WV   = (const float*)d_in[5];
    const float* Wout = (const float*)d_in[6];
    float* out = (float*)d_out;
    u16*  Xbf = (u16*)d_out;            // d_out doubles as bf16 scratch (33.5 MB)

    // ws: [3][B*H*S*64] bf16 (wq, wk, wvT) 50.3 MB + [4][512*512] bf16 2 MB
    const size_t per = (size_t)BATCH * NHEAD * S_LEN * KHD;
    u16* wsQKV = (u16*)d_ws;
    u16* wsW   = wsQKV + 3 * per;

    // 1. weights -> bf16
    wcvt_kernel<<<dim3(256, 4), 256, 0, stream>>>(WQ, WK, WV, Wout, wsW);

    // 2. q,k -> bf16 into d_out (two halves)
    xcvt_kernel<<<dim3(NROW * DMODEL / 1024, 2), 256, 0, stream>>>(q, k, Xbf);

    // 3. q,k projections + norm -> wq, wk
    gemm_kernel<1><<<dim3(NROW / 128, DMODEL / 128, 2), 256, 0, stream>>>(
        Xbf, wsW, wsQKV, nullptr);

    // 4. v -> bf16 into d_out lo half (q-bf16 now dead)
    xcvt_kernel<<<dim3(NROW * DMODEL / 1024, 1), 256, 0, stream>>>(v, v, Xbf);

    // 5. v projection + norm -> transposed wvT [B][H][64][S]
    gemm_kernel<2><<<dim3(S_LEN / 128, DMODEL / 128, BATCH), 256, 0, stream>>>(
        Xbf, wsW + (size_t)2 * DMODEL * DMODEL, wsQKV + 2 * per, nullptr);

    // 6. attention -> bf16 concat into d_out lo half
    //    grid (bh, qt): same-head q-tiles share an XCD -> K/V L2-resident
    attn_kernel<<<dim3(BATCH * NHEAD, S_LEN / 64), 256, 0, stream>>>(
        wsQKV, wsQKV + per, wsQKV + 2 * per, Xbf);

    // 7. move bf16 concat into ws (wq region is dead) so out-proj can write
    //    d_out without racing its own input
    hipMemcpyAsync(wsQKV, Xbf, (size_t)NROW * DMODEL * sizeof(u16),
                   hipMemcpyDeviceToDevice, stream);

    // 8. output projection -> fp32 d_out
    gemm_kernel<0><<<dim3(NROW / 128, DMODEL / 128, 1), 256, 0, stream>>>(
        wsQKV, wsW + (size_t)3 * DMODEL * DMODEL, nullptr, out);
}

// Round 2
// 260.130 us; speedup vs baseline: 1.0779x; 1.0548x over previous
//
#include <hip/hip_runtime.h>
#include <cstdint>
#include <cstddef>

typedef unsigned int u32;
typedef unsigned short u16;
typedef __attribute__((ext_vector_type(8))) short short8;   // 8 bf16 = 4 VGPRs (MFMA A/B frag)
typedef __attribute__((ext_vector_type(4))) float f32x4;    // MFMA C/D frag

#define S_LEN 1024
#define BATCH 16
#define NHEAD 8
#define DMODEL 512
#define KHD 64
#define NROW (S_LEN * BATCH)          // 16384 GEMM rows

__device__ __forceinline__ u16 f2bf(float f) {
    u32 u = __float_as_uint(f);
    return (u16)((u + 0x7fffu + ((u >> 16) & 1u)) >> 16);   // RTNE
}

__device__ __forceinline__ void gl_lds16(const void* g, void* l) {
    __builtin_amdgcn_global_load_lds(
        (const __attribute__((address_space(1))) void*)(uintptr_t)g,
        (__attribute__((address_space(3))) void*)(uintptr_t)l, 16, 0, 0);
}

// ---------------------------------------------------------------------------
// Weights fp32 -> bf16, packed [4][512*512] into ws.
// ---------------------------------------------------------------------------
__global__ __launch_bounds__(256) void wcvt_kernel(
    const float* __restrict__ WQ, const float* __restrict__ WK,
    const float* __restrict__ WV, const float* __restrict__ Wo,
    u16* __restrict__ dst)
{
    const int m = blockIdx.y;
    const float* __restrict__ src = (m == 0) ? WQ : (m == 1) ? WK : (m == 2) ? WV : Wo;
    const int idx = (blockIdx.x * 256 + threadIdx.x) * 4;
    const float4 v = *(const float4*)(src + idx);
    u16 r[4];
    r[0] = f2bf(v.x); r[1] = f2bf(v.y); r[2] = f2bf(v.z); r[3] = f2bf(v.w);
    *(uint2*)(dst + (size_t)m * DMODEL * DMODEL + idx) = *(uint2*)r;
}

// ---------------------------------------------------------------------------
// Activation fp32 -> bf16 (layout-preserving). blockIdx.y picks s0/s1 and the
// destination half (dst + y*NROW*DMODEL).
// ---------------------------------------------------------------------------
__global__ __launch_bounds__(256) void xcvt_kernel(
    const float* __restrict__ s0, const float* __restrict__ s1,
    u16* __restrict__ dst)
{
    const float* __restrict__ src = (blockIdx.y == 0) ? s0 : s1;
    u16* d = dst + (size_t)blockIdx.y * NROW * DMODEL;
    const int idx = (blockIdx.x * 256 + threadIdx.x) * 4;
    const float4 v = *(const float4*)(src + idx);
    u16 r[4];
    r[0] = f2bf(v.x); r[1] = f2bf(v.y); r[2] = f2bf(v.z); r[3] = f2bf(v.w);
    *(uint2*)(d + idx) = *(uint2*)r;
}

// ---------------------------------------------------------------------------
// bf16-MFMA GEMM, 128x128 tile, BK=64. A and B both staged via
// global_load_lds width=16 with XOR chunk swizzle in the GLOBAL address
// (LDS side lane-contiguous) -> conflict-free b128 frag reads, zero VALU
// conversion in the K-loop.
// M==0: fp32 out to outP.                                 grid (128,4,1)
// M==1: per-head L2 norm, bf16 out [B][H][S][64], z=q/k.  grid (128,4,2)
// M==2: per-head L2 norm, V transposed out [B][H][64][S]. grid (8,4,16)
//       A rows are consecutive s for batch bb (astr = B*D).
// ---------------------------------------------------------------------------
template<int M>
__global__ __launch_bounds__(256) void gemm_kernel(
    const u16* __restrict__ Abf,    // bf16 A base (M1: +z*NROW*D; M2: +bb*D)
    const u16* __restrict__ Wb,     // bf16 weight panel (M1: +z*D*D inside)
    u16* __restrict__ outN,
    float* __restrict__ outP)
{
    __shared__ __align__(16) u16 Alds[128 * 64];
    __shared__ __align__(16) u16 Blds[128 * 64];

    const int tid  = threadIdx.x;
    const int wave = tid >> 6;
    const int lane = tid & 63;
    const int m16  = lane & 15;
    const int quad = lane >> 4;
    const int wm   = wave >> 1;
    const int wn   = wave & 1;
    const int n0   = blockIdx.y * 128;
    const int row0 = blockIdx.x * 128;
    const int z    = (M == 1) ? blockIdx.z : 0;
    const int bb   = (M == 2) ? blockIdx.z : 0;

    const u16* __restrict__ A = Abf + (size_t)z * NROW * DMODEL + (size_t)bb * DMODEL;
    const size_t astr = (M == 2) ? (size_t)BATCH * DMODEL : (size_t)DMODEL;
    const u16* __restrict__ B = Wb + ((M == 1) ? (size_t)z * DMODEL * DMODEL : 0);

    f32x4 acc[4][4] = {};

    const int brow   = lane >> 3;              // 0..7
    const int bchunk = (lane & 7) ^ brow;      // XOR chunk swizzle

    for (int kt = 0; kt < DMODEL; kt += 64) {
        __syncthreads();   // previous-iteration frag reads done
        {
            const u16* ap = A + (size_t)(row0 + wave * 32 + brow) * astr + kt + bchunk * 8;
            const u16* bp = B + (size_t)(n0 + wave * 32 + brow) * DMODEL + kt + bchunk * 8;
            u16* la = &Alds[(wave * 32) * 64];
            u16* lb = &Blds[(wave * 32) * 64];
#pragma unroll
            for (int j = 0; j < 4; j++) {
                gl_lds16(ap + (size_t)j * 8 * astr,   la + j * 8 * 64);
                gl_lds16(bp + (size_t)j * 8 * DMODEL, lb + j * 8 * 64);
            }
        }
        __syncthreads();   // drains vmcnt: tiles visible

#pragma unroll
        for (int half = 0; half < 2; half++) {
            short8 af[4], bfr[4];
#pragma unroll
            for (int mt = 0; mt < 4; mt++)
                af[mt] = *(const short8*)&Alds[(wm * 64 + mt * 16 + m16) * 64 +
                                               (((half << 2) + quad) ^ (m16 & 7)) * 8];
#pragma unroll
            for (int nt = 0; nt < 4; nt++)
                bfr[nt] = *(const short8*)&Blds[(wn * 64 + nt * 16 + m16) * 64 +
                                                (((half << 2) + quad) ^ (m16 & 7)) * 8];
#pragma unroll
            for (int mt = 0; mt < 4; mt++)
#pragma unroll
                for (int nt = 0; nt < 4; nt++)
                    acc[mt][nt] = __builtin_amdgcn_mfma_f32_16x16x32_bf16(af[mt], bfr[nt], acc[mt][nt], 0, 0, 0);
        }
    }

    if (M == 1) {
        const int h = (n0 >> 6) + wn;
        u16* outZ = outN + (size_t)z * BATCH * NHEAD * S_LEN * KHD;
#pragma unroll
        for (int mt = 0; mt < 4; mt++) {
#pragma unroll
            for (int r = 0; r < 4; r++) {
                float ss = 0.0f;
#pragma unroll
                for (int nt = 0; nt < 4; nt++) ss += acc[mt][nt][r] * acc[mt][nt][r];
                ss += __shfl_xor(ss, 1);
                ss += __shfl_xor(ss, 2);
                ss += __shfl_xor(ss, 4);
                ss += __shfl_xor(ss, 8);
                const float sc = 1.0f / fmaxf(sqrtf(ss), 1e-12f);
                const int i = row0 + wm * 64 + mt * 16 + quad * 4 + r;
                const int s = i >> 4, b = i & 15;
                u16* op = outZ + (((size_t)b * NHEAD + h) * S_LEN + s) * KHD;
#pragma unroll
                for (int nt = 0; nt < 4; nt++)
                    op[nt * 16 + m16] = f2bf(acc[mt][nt][r] * sc);
            }
        }
    } else if (M == 2) {
        const int h = (n0 >> 6) + wn;
#pragma unroll
        for (int mt = 0; mt < 4; mt++) {
            float scl[4];
#pragma unroll
            for (int r = 0; r < 4; r++) {
                float ss = 0.0f;
#pragma unroll
                for (int nt = 0; nt < 4; nt++) ss += acc[mt][nt][r] * acc[mt][nt][r];
                ss += __shfl_xor(ss, 1);
                ss += __shfl_xor(ss, 2);
                ss += __shfl_xor(ss, 4);
                ss += __shfl_xor(ss, 8);
                scl[r] = 1.0f / fmaxf(sqrtf(ss), 1e-12f);
            }
            const int sbase = row0 + wm * 64 + mt * 16 + quad * 4;
#pragma unroll
            for (int nt = 0; nt < 4; nt++) {
                const int vcol = nt * 16 + m16;
                uint2 pk;
                pk.x = (u32)f2bf(acc[mt][nt][0] * scl[0]) |
                       ((u32)f2bf(acc[mt][nt][1] * scl[1]) << 16);
                pk.y = (u32)f2bf(acc[mt][nt][2] * scl[2]) |
                       ((u32)f2bf(acc[mt][nt][3] * scl[3]) << 16);
                u16* dp = outN + (((size_t)bb * NHEAD + h) * KHD + vcol) * S_LEN + sbase;
                *(uint2*)dp = pk;
            }
        }
    } else {
#pragma unroll
        for (int mt = 0; mt < 4; mt++) {
#pragma unroll
            for (int r = 0; r < 4; r++) {
                const int i = row0 + wm * 64 + mt * 16 + quad * 4 + r;
                float* op = outP + (size_t)i * DMODEL + n0 + wn * 64;
#pragma unroll
                for (int nt = 0; nt < 4; nt++)
                    op[nt * 16 + m16] = acc[mt][nt][r];
            }
        }
    }
}

// ---------------------------------------------------------------------------
// Attention v5. 128 q/block (32 per wave), 64-key iters, grid (128,8):
//   blockIdx.x = bh -> all q-tiles of one head on ONE XCD (linear%8 = bh%8);
//   per-XCD K/V working set = 16 heads x 256KB = 4MB = L2.
// Each wave reads the whole K/V tile ONCE per iter for 32 q (2x the q-work
// of v4 per fragment byte) -> per-q LDS-pipe traffic halves; LDS was the
// binding pipe (~51us of 63us). Staging + logical K/V fetch also halve.
// Double-buffered K/V (stage(next) -> compute(cur) -> barrier, one barrier
// per iter). P staged per 32-key half in a per-wave [16q][32k] buffer
// (write mt=2c,2c+1 -> read -> PV -> reuse): LDS = 16+16+8 = 40KB exactly
// -> 4 blocks/CU.
// Plds swizzle: 64B rows, 16B chunk ^= (m16>>1)&3 -> conflict-free b128.
// Scores = cos/8 in [-0.125,0.125]:
//   p = exp(y/8) via QUADRATIC Taylor (2 FMA, err y^3/3072 <= 3.3e-4,
//   << bf16 pack noise 4e-3); pack via single v_perm_b32 (truncation);
//   row-sum via ones-MFMA on the packed bf16 P -> exact num/denom
//   consistency, zero shuffles.
// Output: bf16 concat [S][B][H*K] -> Xc (= d_out scratch).
// ---------------------------------------------------------------------------
__global__ __launch_bounds__(256, 4) void attn_kernel(
    const u16* __restrict__ wq, const u16* __restrict__ wk, const u16* __restrict__ wvT,
    u16* __restrict__ Xc)
{
    __shared__ __align__(16) u16 Klds[2][64 * 64];    // [buf][key][dim], XOR chunks
    __shared__ __align__(16) u16 Vlds[2][64 * 64];    // [buf][vcol][key], XOR chunks
    __shared__ __align__(16) u16 Plds[4][2][16 * 32]; // [wave][qb][q16][key32], XOR chunks

    const int tid  = threadIdx.x;
    const int wave = tid >> 6;
    const int lane = tid & 63;
    const int m16  = lane & 15;
    const int quad = lane >> 4;
    const int bh   = blockIdx.x;        // 0..127  (XCD = bh % 8)
    const int qt   = blockIdx.y;        // 8 tiles of 128 q

    const u16* Qb = wq  + (size_t)bh * S_LEN * KHD;
    const u16* Kb = wk  + (size_t)bh * S_LEN * KHD;
    const u16* Vb = wvT + (size_t)bh * KHD * S_LEN;

    // 32 q rows per wave: qb=0 -> qr0, qb=1 -> qr0+16
    const int qr0 = qt * 128 + wave * 32 + m16;
    short8 qf[2][2];
    qf[0][0] = *(const short8*)(Qb + (size_t)qr0 * KHD + quad * 8);
    qf[0][1] = *(const short8*)(Qb + (size_t)qr0 * KHD + 32 + quad * 8);
    qf[1][0] = *(const short8*)(Qb + (size_t)(qr0 + 16) * KHD + quad * 8);
    qf[1][1] = *(const short8*)(Qb + (size_t)(qr0 + 16) * KHD + 32 + quad * 8);

    short8 ones;
#pragma unroll
    for (int j = 0; j < 8; j++) ones[j] = (short)0x3F80;   // bf16 1.0

    f32x4 o[2][4] = {};   // [qb][vt]: D[m=vcol][n=q]
    f32x4 ls[2]   = {};   // [qb] ones-MFMA row-sum accumulator
    const float C1 = 0.125f, C2 = 0.0078125f;   // exp(y/8) ~= 1 + y/8 + y^2/128

    const int srow   = lane >> 3;
    const int schunk = (lane & 7) ^ srow;
    const int r0     = wave * 8 + srow;
    const int pswz   = (m16 >> 1) & 3;          // Plds chunk XOR

    // prologue: stage tile 0 into buf 0
    gl_lds16(Kb + (size_t)r0 * KHD + schunk * 8,               &Klds[0][(wave * 8) * 64]);
    gl_lds16(Kb + (size_t)(r0 + 32) * KHD + schunk * 8,        &Klds[0][(wave * 8 + 32) * 64]);
    gl_lds16(Vb + (size_t)r0 * S_LEN + schunk * 8,             &Vlds[0][(wave * 8) * 64]);
    gl_lds16(Vb + (size_t)(r0 + 32) * S_LEN + schunk * 8,      &Vlds[0][(wave * 8 + 32) * 64]);
    __syncthreads();

    for (int it = 0; it < S_LEN / 64; it++) {
        const int cur = it & 1;

        // stage NEXT tile into the other buffer; latency hides under compute
        if (it + 1 < S_LEN / 64) {
            const int nxt = cur ^ 1;
            const int kt0 = (it + 1) * 64;
            gl_lds16(Kb + (size_t)(kt0 + r0) * KHD + schunk * 8,        &Klds[nxt][(wave * 8) * 64]);
            gl_lds16(Kb + (size_t)(kt0 + r0 + 32) * KHD + schunk * 8,   &Klds[nxt][(wave * 8 + 32) * 64]);
            gl_lds16(Vb + (size_t)r0 * S_LEN + kt0 + schunk * 8,        &Vlds[nxt][(wave * 8) * 64]);
            gl_lds16(Vb + (size_t)(r0 + 32) * S_LEN + kt0 + schunk * 8, &Vlds[nxt][(wave * 8 + 32) * 64]);
        }

#pragma unroll
        for (int cc = 0; cc < 2; cc++) {
            // S^T for keys cc*32..cc*32+31: D[m=key][n=q] = K x Q^T
#pragma unroll
            for (int mm = 0; mm < 2; mm++) {
                const int mt = cc * 2 + mm;
                const short8 kf0 = *(const short8*)&Klds[cur][(mt * 16 + m16) * 64 + (quad ^ (m16 & 7)) * 8];
                const short8 kf1 = *(const short8*)&Klds[cur][(mt * 16 + m16) * 64 + ((4 + quad) ^ (m16 & 7)) * 8];
#pragma unroll
                for (int qb = 0; qb < 2; qb++) {
                    f32x4 s = {};
                    s = __builtin_amdgcn_mfma_f32_16x16x32_bf16(kf0, qf[qb][0], s, 0, 0, 0);
                    s = __builtin_amdgcn_mfma_f32_16x16x32_bf16(kf1, qf[qb][1], s, 0, 0, 0);
                    u32 up[4];
#pragma unroll
                    for (int r = 0; r < 4; r++) {
                        const float y = s[r];
                        const float p = fmaf(fmaf(C2, y, C1), y, 1.0f);
                        up[r] = __float_as_uint(p);
                    }
                    uint2 pk;   // truncation-pack two bf16 per u32 via byte-perm
                    pk.x = __builtin_amdgcn_perm(up[1], up[0], 0x07060302u);
                    pk.y = __builtin_amdgcn_perm(up[3], up[2], 0x07060302u);
                    // logical: row m16 (64B), chunk = mm*2 + quad>>1, half = quad&1
                    *(uint2*)((char*)&Plds[wave][qb][0] + m16 * 64 +
                              ((((mm << 1) + (quad >> 1)) ^ pswz) << 4) + ((quad & 1) << 3)) = pk;
                }
            }

            // PV for this 32-key half + ones-MFMA row-sum (wave-private P)
            short8 vfr[4];
#pragma unroll
            for (int vt = 0; vt < 4; vt++)
                vfr[vt] = *(const short8*)&Vlds[cur][(vt * 16 + m16) * 64 +
                                                     (((cc << 2) + quad) ^ (m16 & 7)) * 8];
            __builtin_amdgcn_s_setprio(1);
#pragma unroll
            for (int qb = 0; qb < 2; qb++) {
                const short8 pb = *(const short8*)((const char*)&Plds[wave][qb][0] + m16 * 64 +
                                                   ((quad ^ pswz) << 4));
                ls[qb] = __builtin_amdgcn_mfma_f32_16x16x32_bf16(ones, pb, ls[qb], 0, 0, 0);
#pragma unroll
                for (int vt = 0; vt < 4; vt++)
                    o[qb][vt] = __builtin_amdgcn_mfma_f32_16x16x32_bf16(vfr[vt], pb, o[qb][vt], 0, 0, 0);
            }
            __builtin_amdgcn_s_setprio(0);
        }

        __syncthreads();   // drains vmcnt (next tile visible) + frees cur buf
    }

    // epilogue: lane's q = m16 (all ls regs hold that q's row-sum)
    const int b = bh >> 3, h = bh & 7;
#pragma unroll
    for (int qb = 0; qb < 2; qb++) {
        const float inv = 1.0f / ls[qb][0];
        const int qrow = qr0 + qb * 16;
        u16* cp = Xc + ((size_t)qrow * BATCH + b) * (NHEAD * KHD) + h * KHD;
#pragma unroll
        for (int vt = 0; vt < 4; vt++) {
            uint2 pk;
            pk.x = (u32)f2bf(o[qb][vt][0] * inv) | ((u32)f2bf(o[qb][vt][1] * inv) << 16);
            pk.y = (u32)f2bf(o[qb][vt][2] * inv) | ((u32)f2bf(o[qb][vt][3] * inv) << 16);
            *(uint2*)(cp + vt * 16 + quad * 4) = pk;
        }
    }
}

extern "C" void kernel_launch(void* const* d_in, const int* in_sizes, int n_in,
                              void* d_out, int out_size, void* d_ws, size_t ws_size,
                              hipStream_t stream) {
    const float* q    = (const float*)d_in[0];
    const float* k    = (const float*)d_in[1];
    const float* v    = (const float*)d_in[2];
    const float* WQ   = (const float*)d_in[3];
    const float* WK   = (const float*)d_in[4];
    const float* WV   = (const float*)d_in[5];
    const float* Wout = (const float*)d_in[6];
    float* out = (float*)d_out;
    u16*  Xbf = (u16*)d_out;            // d_out doubles as bf16 scratch (33.5 MB)

    // ws: [3][B*H*S*64] bf16 (wq, wk, wvT) 50.3 MB + [4][512*512] bf16 2 MB
    const size_t per = (size_t)BATCH * NHEAD * S_LEN * KHD;
    u16* wsQKV = (u16*)d_ws;
    u16* wsW   = wsQKV + 3 * per;

    // 1. weights -> bf16
    wcvt_kernel<<<dim3(256, 4), 256, 0, stream>>>(WQ, WK, WV, Wout, wsW);

    // 2. q,k -> bf16 into d_out (two halves)
    xcvt_kernel<<<dim3(NROW * DMODEL / 1024, 2), 256, 0, stream>>>(q, k, Xbf);

    // 3. q,k projections + norm -> wq, wk
    gemm_kernel<1><<<dim3(NROW / 128, DMODEL / 128, 2), 256, 0, stream>>>(
        Xbf, wsW, wsQKV, nullptr);

    // 4. v -> bf16 into d_out lo half (q-bf16 now dead)
    xcvt_kernel<<<dim3(NROW * DMODEL / 1024, 1), 256, 0, stream>>>(v, v, Xbf);

    // 5. v projection + norm -> transposed wvT [B][H][64][S]
    gemm_kernel<2><<<dim3(S_LEN / 128, DMODEL / 128, BATCH), 256, 0, stream>>>(
        Xbf, wsW + (size_t)2 * DMODEL * DMODEL, wsQKV + 2 * per, nullptr);

    // 6. attention -> bf16 concat into d_out lo half
    //    grid (bh, qt): same-head q-tiles share an XCD -> K/V L2-resident
    attn_kernel<<<dim3(BATCH * NHEAD, S_LEN / 128), 256, 0, stream>>>(
        wsQKV, wsQKV + per, wsQKV + 2 * per, Xbf);

    // 7. move bf16 concat into ws (wq region is dead) so out-proj can write
    //    d_out without racing its own input
    hipMemcpyAsync(wsQKV, Xbf, (size_t)NROW * DMODEL * sizeof(u16),
                   hipMemcpyDeviceToDevice, stream);

    // 8. output projection -> fp32 d_out
    gemm_kernel<0><<<dim3(NROW / 128, DMODEL / 128, 1), 256, 0, stream>>>(
        wsQKV, wsW + (size_t)3 * DMODEL * DMODEL, nullptr, out);
}

// Round 3
// 250.828 us; speedup vs baseline: 1.1179x; 1.0371x over previous
//
#include <hip/hip_runtime.h>
#include <cstdint>
#include <cstddef>

typedef unsigned int u32;
typedef unsigned short u16;
typedef __attribute__((ext_vector_type(8))) short short8;   // 8 bf16 = 4 VGPRs (MFMA A/B frag)
typedef __attribute__((ext_vector_type(4))) float f32x4;    // MFMA C/D frag

#define S_LEN 1024
#define BATCH 16
#define NHEAD 8
#define DMODEL 512
#define KHD 64
#define NROW (S_LEN * BATCH)          // 16384 GEMM rows

__device__ __forceinline__ u16 f2bf(float f) {
    u32 u = __float_as_uint(f);
    return (u16)((u + 0x7fffu + ((u >> 16) & 1u)) >> 16);   // RTNE
}

__device__ __forceinline__ void gl_lds16(const void* g, void* l) {
    __builtin_amdgcn_global_load_lds(
        (const __attribute__((address_space(1))) void*)(uintptr_t)g,
        (__attribute__((address_space(3))) void*)(uintptr_t)l, 16, 0, 0);
}

// ---------------------------------------------------------------------------
// Weights fp32 -> bf16, packed [4][512*512] into ws.
// ---------------------------------------------------------------------------
__global__ __launch_bounds__(256) void wcvt_kernel(
    const float* __restrict__ WQ, const float* __restrict__ WK,
    const float* __restrict__ WV, const float* __restrict__ Wo,
    u16* __restrict__ dst)
{
    const int m = blockIdx.y;
    const float* __restrict__ src = (m == 0) ? WQ : (m == 1) ? WK : (m == 2) ? WV : Wo;
    const int idx = (blockIdx.x * 256 + threadIdx.x) * 4;
    const float4 v = *(const float4*)(src + idx);
    u16 r[4];
    r[0] = f2bf(v.x); r[1] = f2bf(v.y); r[2] = f2bf(v.z); r[3] = f2bf(v.w);
    *(uint2*)(dst + (size_t)m * DMODEL * DMODEL + idx) = *(uint2*)r;
}

// ---------------------------------------------------------------------------
// Activation fp32 -> bf16 (layout-preserving). blockIdx.y picks s0/s1 and the
// destination half (dst + y*NROW*DMODEL).
// ---------------------------------------------------------------------------
__global__ __launch_bounds__(256) void xcvt_kernel(
    const float* __restrict__ s0, const float* __restrict__ s1,
    u16* __restrict__ dst)
{
    const float* __restrict__ src = (blockIdx.y == 0) ? s0 : s1;
    u16* d = dst + (size_t)blockIdx.y * NROW * DMODEL;
    const int idx = (blockIdx.x * 256 + threadIdx.x) * 4;
    const float4 v = *(const float4*)(src + idx);
    u16 r[4];
    r[0] = f2bf(v.x); r[1] = f2bf(v.y); r[2] = f2bf(v.z); r[3] = f2bf(v.w);
    *(uint2*)(d + idx) = *(uint2*)r;
}

// ---------------------------------------------------------------------------
// bf16-MFMA GEMM, 128x128 tile, BK=64. A and B both staged via
// global_load_lds width=16 with XOR chunk swizzle in the GLOBAL address
// (LDS side lane-contiguous) -> conflict-free b128 frag reads, zero VALU
// conversion in the K-loop.
// M==0: A gathered from [B][H][S][64] (attn concat written in-place into the
//       wq region -> no memcpy); fp32 out to outP.        grid (128,4,1)
// M==1: per-head L2 norm, bf16 out [B][H][S][64], z=q/k.  grid (128,4,2)
// M==2: per-head L2 norm, V transposed out [B][H][64][S]. grid (8,4,16)
//       A rows are consecutive s for batch bb (astr = B*D).
// ---------------------------------------------------------------------------
template<int M>
__global__ __launch_bounds__(256) void gemm_kernel(
    const u16* __restrict__ Abf,    // bf16 A base (M1: +z*NROW*D; M2: +bb*D)
    const u16* __restrict__ Wb,     // bf16 weight panel (M1: +z*D*D inside)
    u16* __restrict__ outN,
    float* __restrict__ outP)
{
    __shared__ __align__(16) u16 Alds[128 * 64];
    __shared__ __align__(16) u16 Blds[128 * 64];

    const int tid  = threadIdx.x;
    const int wave = tid >> 6;
    const int lane = tid & 63;
    const int m16  = lane & 15;
    const int quad = lane >> 4;
    const int wm   = wave >> 1;
    const int wn   = wave & 1;
    const int n0   = blockIdx.y * 128;
    const int row0 = blockIdx.x * 128;
    const int z    = (M == 1) ? blockIdx.z : 0;
    const int bb   = (M == 2) ? blockIdx.z : 0;

    const u16* __restrict__ A = Abf + (size_t)z * NROW * DMODEL + (size_t)bb * DMODEL;
    const size_t astr = (M == 2) ? (size_t)BATCH * DMODEL : (size_t)DMODEL;
    const u16* __restrict__ B = Wb + ((M == 1) ? (size_t)z * DMODEL * DMODEL : 0);

    f32x4 acc[4][4] = {};

    const int brow   = lane >> 3;              // 0..7
    const int bchunk = (lane & 7) ^ brow;      // XOR chunk swizzle

    for (int kt = 0; kt < DMODEL; kt += 64) {
        __syncthreads();   // previous-iteration frag reads done
        {
            u16* la = &Alds[(wave * 32) * 64];
            u16* lb = &Blds[(wave * 32) * 64];
            const u16* bp = B + (size_t)(n0 + wave * 32 + brow) * DMODEL + kt + bchunk * 8;
            if (M == 0) {
                // A lives in [B][H][S][64]: row i = s*16+b, col c = h*64+kk.
                // 16B chunks never straddle a head boundary (8 | 64).
                const int colc = kt + bchunk * 8;
                const int hh   = colc >> 6;
                const int kk   = colc & 63;
#pragma unroll
                for (int j = 0; j < 4; j++) {
                    const int i  = row0 + wave * 32 + brow + j * 8;
                    const int ss = i >> 4, bx = i & 15;
                    gl_lds16(Abf + (((size_t)(bx * NHEAD + hh) * S_LEN + ss) * KHD + kk),
                             la + j * 8 * 64);
                    gl_lds16(bp + (size_t)j * 8 * DMODEL, lb + j * 8 * 64);
                }
            } else {
                const u16* ap = A + (size_t)(row0 + wave * 32 + brow) * astr + kt + bchunk * 8;
#pragma unroll
                for (int j = 0; j < 4; j++) {
                    gl_lds16(ap + (size_t)j * 8 * astr,   la + j * 8 * 64);
                    gl_lds16(bp + (size_t)j * 8 * DMODEL, lb + j * 8 * 64);
                }
            }
        }
        __syncthreads();   // drains vmcnt: tiles visible

#pragma unroll
        for (int half = 0; half < 2; half++) {
            short8 af[4], bfr[4];
#pragma unroll
            for (int mt = 0; mt < 4; mt++)
                af[mt] = *(const short8*)&Alds[(wm * 64 + mt * 16 + m16) * 64 +
                                               (((half << 2) + quad) ^ (m16 & 7)) * 8];
#pragma unroll
            for (int nt = 0; nt < 4; nt++)
                bfr[nt] = *(const short8*)&Blds[(wn * 64 + nt * 16 + m16) * 64 +
                                                (((half << 2) + quad) ^ (m16 & 7)) * 8];
#pragma unroll
            for (int mt = 0; mt < 4; mt++)
#pragma unroll
                for (int nt = 0; nt < 4; nt++)
                    acc[mt][nt] = __builtin_amdgcn_mfma_f32_16x16x32_bf16(af[mt], bfr[nt], acc[mt][nt], 0, 0, 0);
        }
    }

    if (M == 1) {
        const int h = (n0 >> 6) + wn;
        u16* outZ = outN + (size_t)z * BATCH * NHEAD * S_LEN * KHD;
#pragma unroll
        for (int mt = 0; mt < 4; mt++) {
#pragma unroll
            for (int r = 0; r < 4; r++) {
                float ss = 0.0f;
#pragma unroll
                for (int nt = 0; nt < 4; nt++) ss += acc[mt][nt][r] * acc[mt][nt][r];
                ss += __shfl_xor(ss, 1);
                ss += __shfl_xor(ss, 2);
                ss += __shfl_xor(ss, 4);
                ss += __shfl_xor(ss, 8);
                const float sc = 1.0f / fmaxf(sqrtf(ss), 1e-12f);
                const int i = row0 + wm * 64 + mt * 16 + quad * 4 + r;
                const int s = i >> 4, b = i & 15;
                u16* op = outZ + (((size_t)b * NHEAD + h) * S_LEN + s) * KHD;
#pragma unroll
                for (int nt = 0; nt < 4; nt++)
                    op[nt * 16 + m16] = f2bf(acc[mt][nt][r] * sc);
            }
        }
    } else if (M == 2) {
        const int h = (n0 >> 6) + wn;
#pragma unroll
        for (int mt = 0; mt < 4; mt++) {
            float scl[4];
#pragma unroll
            for (int r = 0; r < 4; r++) {
                float ss = 0.0f;
#pragma unroll
                for (int nt = 0; nt < 4; nt++) ss += acc[mt][nt][r] * acc[mt][nt][r];
                ss += __shfl_xor(ss, 1);
                ss += __shfl_xor(ss, 2);
                ss += __shfl_xor(ss, 4);
                ss += __shfl_xor(ss, 8);
                scl[r] = 1.0f / fmaxf(sqrtf(ss), 1e-12f);
            }
            const int sbase = row0 + wm * 64 + mt * 16 + quad * 4;
#pragma unroll
            for (int nt = 0; nt < 4; nt++) {
                const int vcol = nt * 16 + m16;
                uint2 pk;
                pk.x = (u32)f2bf(acc[mt][nt][0] * scl[0]) |
                       ((u32)f2bf(acc[mt][nt][1] * scl[1]) << 16);
                pk.y = (u32)f2bf(acc[mt][nt][2] * scl[2]) |
                       ((u32)f2bf(acc[mt][nt][3] * scl[3]) << 16);
                u16* dp = outN + (((size_t)bb * NHEAD + h) * KHD + vcol) * S_LEN + sbase;
                *(uint2*)dp = pk;
            }
        }
    } else {
#pragma unroll
        for (int mt = 0; mt < 4; mt++) {
#pragma unroll
            for (int r = 0; r < 4; r++) {
                const int i = row0 + wm * 64 + mt * 16 + quad * 4 + r;
                float* op = outP + (size_t)i * DMODEL + n0 + wn * 64;
#pragma unroll
                for (int nt = 0; nt < 4; nt++)
                    op[nt * 16 + m16] = acc[mt][nt][r];
            }
        }
    }
}

// ---------------------------------------------------------------------------
// Attention v6. 256 q/block (64 per wave, qb=0..3), 64-key iters, grid
// (128,4): blockIdx.x = bh -> all q-tiles of one head on ONE XCD
// (linear%8 = bh%8); per-XCD K/V working set = 16 heads x 256KB = 4MB = L2.
// R1 pipe model: attn is LDS-pipe-bound (~83%). Each wave reads the whole
// 8KB K-tile + 8KB V-tile once per iter; qb=4 amortizes those reads over
// 64 q (2x v5) -> per-q LDS cost 10 -> 6.5 cy. LDS = 16(K)+16(V)+16(P)
// = 48KB, VGPR ~160 -> 2 blocks/CU (grid 512 = exactly 2/CU resident).
// Double-buffered K/V (stage(next) -> compute(cur) -> barrier). P staged
// per 32-key half in per-wave-per-qb [16q][32k] buffers.
// Plds swizzle: 64B rows, 16B chunk ^= (m16>>1)&3 -> conflict-free b128.
// Scores = cos/8 in [-0.125,0.125]:
//   p = exp(y/8) via QUADRATIC Taylor (2 FMA, err y^3/3072 <= 3.3e-4,
//   << bf16 pack noise 4e-3); pack via single v_perm_b32 (truncation);
//   row-sum via ones-MFMA on the packed bf16 P -> exact num/denom
//   consistency, zero shuffles.
// Output written DIRECTLY into the wq region in [B][H][S][64] layout:
// each block reads only its own Q slice (prologue, regs) and writes only
// its own slice (epilogue) -> no race, and the memcpy step dies.
// ---------------------------------------------------------------------------
__global__ __launch_bounds__(256, 2) void attn_kernel(
    const u16* __restrict__ wq, const u16* __restrict__ wk, const u16* __restrict__ wvT,
    u16* __restrict__ Xout)     // = wq base, [B][H][S][64]
{
    __shared__ __align__(16) u16 Klds[2][64 * 64];    // [buf][key][dim], XOR chunks
    __shared__ __align__(16) u16 Vlds[2][64 * 64];    // [buf][vcol][key], XOR chunks
    __shared__ __align__(16) u16 Plds[4][4][16 * 32]; // [wave][qb][q16][key32], XOR chunks

    const int tid  = threadIdx.x;
    const int wave = tid >> 6;
    const int lane = tid & 63;
    const int m16  = lane & 15;
    const int quad = lane >> 4;
    const int bh   = blockIdx.x;        // 0..127  (XCD = bh % 8)
    const int qt   = blockIdx.y;        // 4 tiles of 256 q

    const u16* Qb = wq  + (size_t)bh * S_LEN * KHD;
    const u16* Kb = wk  + (size_t)bh * S_LEN * KHD;
    const u16* Vb = wvT + (size_t)bh * KHD * S_LEN;

    // 64 q rows per wave: row = qr0 + qb*16 + m16
    const int qr0 = qt * 256 + wave * 64;
    short8 qf[4][2];
#pragma unroll
    for (int qb = 0; qb < 4; qb++) {
        qf[qb][0] = *(const short8*)(Qb + (size_t)(qr0 + qb * 16 + m16) * KHD + quad * 8);
        qf[qb][1] = *(const short8*)(Qb + (size_t)(qr0 + qb * 16 + m16) * KHD + 32 + quad * 8);
    }

    short8 ones;
#pragma unroll
    for (int j = 0; j < 8; j++) ones[j] = (short)0x3F80;   // bf16 1.0

    f32x4 o[4][4] = {};   // [qb][vt]: D[m=vcol][n=q]
    f32x4 ls[4]   = {};   // [qb] ones-MFMA row-sum accumulator
    const float C1 = 0.125f, C2 = 0.0078125f;   // exp(y/8) ~= 1 + y/8 + y^2/128

    const int srow   = lane >> 3;
    const int schunk = (lane & 7) ^ srow;
    const int r0     = wave * 8 + srow;
    const int pswz   = (m16 >> 1) & 3;          // Plds chunk XOR

    // prologue: stage tile 0 into buf 0
    gl_lds16(Kb + (size_t)r0 * KHD + schunk * 8,               &Klds[0][(wave * 8) * 64]);
    gl_lds16(Kb + (size_t)(r0 + 32) * KHD + schunk * 8,        &Klds[0][(wave * 8 + 32) * 64]);
    gl_lds16(Vb + (size_t)r0 * S_LEN + schunk * 8,             &Vlds[0][(wave * 8) * 64]);
    gl_lds16(Vb + (size_t)(r0 + 32) * S_LEN + schunk * 8,      &Vlds[0][(wave * 8 + 32) * 64]);
    __syncthreads();

    for (int it = 0; it < S_LEN / 64; it++) {
        const int cur = it & 1;

        // stage NEXT tile into the other buffer; latency hides under compute
        if (it + 1 < S_LEN / 64) {
            const int nxt = cur ^ 1;
            const int kt0 = (it + 1) * 64;
            gl_lds16(Kb + (size_t)(kt0 + r0) * KHD + schunk * 8,        &Klds[nxt][(wave * 8) * 64]);
            gl_lds16(Kb + (size_t)(kt0 + r0 + 32) * KHD + schunk * 8,   &Klds[nxt][(wave * 8 + 32) * 64]);
            gl_lds16(Vb + (size_t)r0 * S_LEN + kt0 + schunk * 8,        &Vlds[nxt][(wave * 8) * 64]);
            gl_lds16(Vb + (size_t)(r0 + 32) * S_LEN + kt0 + schunk * 8, &Vlds[nxt][(wave * 8 + 32) * 64]);
        }

#pragma unroll
        for (int cc = 0; cc < 2; cc++) {
            // S^T for keys cc*32..cc*32+31: D[m=key][n=q] = K x Q^T
#pragma unroll
            for (int mm = 0; mm < 2; mm++) {
                const int mt = cc * 2 + mm;
                const short8 kf0 = *(const short8*)&Klds[cur][(mt * 16 + m16) * 64 + (quad ^ (m16 & 7)) * 8];
                const short8 kf1 = *(const short8*)&Klds[cur][(mt * 16 + m16) * 64 + ((4 + quad) ^ (m16 & 7)) * 8];
#pragma unroll
                for (int qb = 0; qb < 4; qb++) {
                    f32x4 s = {};
                    s = __builtin_amdgcn_mfma_f32_16x16x32_bf16(kf0, qf[qb][0], s, 0, 0, 0);
                    s = __builtin_amdgcn_mfma_f32_16x16x32_bf16(kf1, qf[qb][1], s, 0, 0, 0);
                    u32 up[4];
#pragma unroll
                    for (int r = 0; r < 4; r++) {
                        const float y = s[r];
                        const float p = fmaf(fmaf(C2, y, C1), y, 1.0f);
                        up[r] = __float_as_uint(p);
                    }
                    uint2 pk;   // truncation-pack two bf16 per u32 via byte-perm
                    pk.x = __builtin_amdgcn_perm(up[1], up[0], 0x07060302u);
                    pk.y = __builtin_amdgcn_perm(up[3], up[2], 0x07060302u);
                    // logical: row m16 (64B), chunk = mm*2 + quad>>1, half = quad&1
                    *(uint2*)((char*)&Plds[wave][qb][0] + m16 * 64 +
                              ((((mm << 1) + (quad >> 1)) ^ pswz) << 4) + ((quad & 1) << 3)) = pk;
                }
            }

            // PV for this 32-key half + ones-MFMA row-sum (wave-private P)
            short8 vfr[4];
#pragma unroll
            for (int vt = 0; vt < 4; vt++)
                vfr[vt] = *(const short8*)&Vlds[cur][(vt * 16 + m16) * 64 +
                                                     (((cc << 2) + quad) ^ (m16 & 7)) * 8];
            __builtin_amdgcn_s_setprio(1);
#pragma unroll
            for (int qb = 0; qb < 4; qb++) {
                const short8 pb = *(const short8*)((const char*)&Plds[wave][qb][0] + m16 * 64 +
                                                   ((quad ^ pswz) << 4));
                ls[qb] = __builtin_amdgcn_mfma_f32_16x16x32_bf16(ones, pb, ls[qb], 0, 0, 0);
#pragma unroll
                for (int vt = 0; vt < 4; vt++)
                    o[qb][vt] = __builtin_amdgcn_mfma_f32_16x16x32_bf16(vfr[vt], pb, o[qb][vt], 0, 0, 0);
            }
            __builtin_amdgcn_s_setprio(0);
        }

        __syncthreads();   // drains vmcnt (next tile visible) + frees cur buf
    }

    // epilogue: lane's q = m16; write into wq region, [B][H][S][64] layout.
    u16* outB = Xout + (size_t)bh * S_LEN * KHD;
#pragma unroll
    for (int qb = 0; qb < 4; qb++) {
        const float inv = 1.0f / ls[qb][0];
        const int qrow = qr0 + qb * 16 + m16;
        u16* cp = outB + (size_t)qrow * KHD;
#pragma unroll
        for (int vt = 0; vt < 4; vt++) {
            uint2 pk;
            pk.x = (u32)f2bf(o[qb][vt][0] * inv) | ((u32)f2bf(o[qb][vt][1] * inv) << 16);
            pk.y = (u32)f2bf(o[qb][vt][2] * inv) | ((u32)f2bf(o[qb][vt][3] * inv) << 16);
            *(uint2*)(cp + vt * 16 + quad * 4) = pk;
        }
    }
}

extern "C" void kernel_launch(void* const* d_in, const int* in_sizes, int n_in,
                              void* d_out, int out_size, void* d_ws, size_t ws_size,
                              hipStream_t stream) {
    const float* q    = (const float*)d_in[0];
    const float* k    = (const float*)d_in[1];
    const float* v    = (const float*)d_in[2];
    const float* WQ   = (const float*)d_in[3];
    const float* WK   = (const float*)d_in[4];
    const float* WV   = (const float*)d_in[5];
    const float* Wout = (const float*)d_in[6];
    float* out = (float*)d_out;
    u16*  Xbf = (u16*)d_out;            // d_out doubles as bf16 scratch (33.5 MB)

    // ws: [3][B*H*S*64] bf16 (wq, wk, wvT) 50.3 MB + [4][512*512] bf16 2 MB
    const size_t per = (size_t)BATCH * NHEAD * S_LEN * KHD;
    u16* wsQKV = (u16*)d_ws;
    u16* wsW   = wsQKV + 3 * per;

    // 1. weights -> bf16
    wcvt_kernel<<<dim3(256, 4), 256, 0, stream>>>(WQ, WK, WV, Wout, wsW);

    // 2. q,k -> bf16 into d_out (two halves)
    xcvt_kernel<<<dim3(NROW * DMODEL / 1024, 2), 256, 0, stream>>>(q, k, Xbf);

    // 3. q,k projections + norm -> wq, wk
    gemm_kernel<1><<<dim3(NROW / 128, DMODEL / 128, 2), 256, 0, stream>>>(
        Xbf, wsW, wsQKV, nullptr);

    // 4. v -> bf16 into d_out lo half (q-bf16 now dead)
    xcvt_kernel<<<dim3(NROW * DMODEL / 1024, 1), 256, 0, stream>>>(v, v, Xbf);

    // 5. v projection + norm -> transposed wvT [B][H][64][S]
    gemm_kernel<2><<<dim3(S_LEN / 128, DMODEL / 128, BATCH), 256, 0, stream>>>(
        Xbf, wsW + (size_t)2 * DMODEL * DMODEL, wsQKV + 2 * per, nullptr);

    // 6. attention -> concat written in-place into the wq region
    //    ([B][H][S][64]); each block touches only its own slice -> no race
    attn_kernel<<<dim3(BATCH * NHEAD, S_LEN / 256), 256, 0, stream>>>(
        wsQKV, wsQKV + per, wsQKV + 2 * per, wsQKV);

    // 7. output projection (A gathered from [B][H][S][64]) -> fp32 d_out
    gemm_kernel<0><<<dim3(NROW / 128, DMODEL / 128, 1), 256, 0, stream>>>(
        wsQKV, wsW + (size_t)3 * DMODEL * DMODEL, nullptr, out);
}